// Round 5
// baseline (445.004 us; speedup 1.0000x reference)
//
#include <hip/hip_runtime.h>
#include <cstdint>
#include <cmath>

#define N0c 247808
#define N1c 22528
#define NBc 2048
#define E0c 225280
#define E1c 20480
#define Cc  256
#define NDST (N1c + NBc)          // 24576 = 24*1024 concatenated CSR rows
#define ETOT (E0c + E1c)          // 245760

typedef __attribute__((ext_vector_type(8))) short short8;   // 8 bf16 in 4 VGPRs
typedef __attribute__((ext_vector_type(4))) float floatx4;  // MFMA C/D frag

__device__ inline unsigned short f2bf(float f) {            // f32 -> bf16 RNE
    union { float f; unsigned u; } cv; cv.f = f;
    unsigned u = cv.u;
    u += 0x7fffu + ((u >> 16) & 1u);
    return (unsigned short)(u >> 16);
}
__device__ inline float bf2f(unsigned short u) {            // bf16 -> f32
    union { unsigned u; float f; } cv; cv.u = ((unsigned)u) << 16;
    return cv.f;
}

// ---------- fused prep: degree count (blocks 0..959) + W pack (960..1087) ----------
// pack layout: [nt(16)][kt(16)][lane(64)][8 bf16]; lane holds
// B[k=kt*32+(lane>>4)*8+j][n=nt*16+(lane&15)], W = [Wrel;Wroot] (K=512)
__global__ __launch_bounds__(256) void prep_kernel(
    const int* __restrict__ dst0, const int* __restrict__ dst1, int* __restrict__ cnt,
    const float* __restrict__ Wrel0, const float* __restrict__ Wroot0,
    const float* __restrict__ Wrel1, const float* __restrict__ Wroot1,
    short* __restrict__ Wp0, short* __restrict__ Wp1) {
    int b = blockIdx.x;
    if (b < ETOT / 256) {
        int e = b * 256 + threadIdx.x;
        if (e < E0c) atomicAdd(&cnt[dst0[e]], 1);
        else         atomicAdd(&cnt[N1c + dst1[e - E0c]], 1);
    } else {
        int gid = (b - ETOT / 256) * 256 + threadIdx.x;   // 0..32767
        int lane = gid & 63;
        int kt = (gid >> 6) & 15;
        int nt = (gid >> 10) & 15;
        int layer = gid >> 14;
        const float* Wrel  = layer ? Wrel1  : Wrel0;
        const float* Wroot = layer ? Wroot1 : Wroot0;
        short* Wp = layer ? Wp1 : Wp0;
        int nn = nt * 16 + (lane & 15);
        int kb = kt * 32 + (lane >> 4) * 8;
        short8 v;
#pragma unroll
        for (int j = 0; j < 8; j++) {
            int k = kb + j;
            float f = (k < 256) ? Wrel[k * 256 + nn] : Wroot[(k - 256) * 256 + nn];
            v[j] = (short)f2bf(f);
        }
        *(short8*)(Wp + (((size_t)nt * 16 + kt) * 64 + lane) * 8) = v;
    }
}

// ---------- scan stage 1: per-1024-chunk exclusive scan + chunk totals ----------
__global__ __launch_bounds__(256) void scan_part(const int* __restrict__ in,
                                                 int* __restrict__ out,
                                                 int* __restrict__ partials) {
    __shared__ int wsum[4];
    int t = threadIdx.x, lane = t & 63, w = t >> 6;
    int base = blockIdx.x * 1024 + t * 4;
    int4 v = *(const int4*)(in + base);
    int s = v.x + v.y + v.z + v.w;
    int incl = s;
#pragma unroll
    for (int o = 1; o < 64; o <<= 1) {
        int u = __shfl_up(incl, o);
        if (lane >= o) incl += u;
    }
    if (lane == 63) wsum[w] = incl;
    __syncthreads();
    int woff = 0;
    for (int j = 0; j < w; j++) woff += wsum[j];
    int excl = woff + incl - s;
    int4 o4;
    o4.x = excl; excl += v.x;
    o4.y = excl; excl += v.y;
    o4.z = excl; excl += v.z;
    o4.w = excl; excl += v.w;
    *(int4*)(out + base) = o4;
    if (t == 255) partials[blockIdx.x] = woff + incl;
}

// ---------- scan stage 2: re-scan 24 partials in-wave, add, emit cur & total ----------
__global__ __launch_bounds__(256) void scan_add(int* __restrict__ off, int* __restrict__ cur,
                                                const int* __restrict__ partials) {
    __shared__ int pfx_s;
    int t = threadIdx.x;
    if (t < 32) {
        int v = (t < NDST / 1024) ? partials[t] : 0;
        int incl = v;
#pragma unroll
        for (int o = 1; o < 32; o <<= 1) {
            int u = __shfl_up(incl, o);
            if (t >= o) incl += u;
        }
        if (t == (int)blockIdx.x) pfx_s = incl - v;       // exclusive prefix for this block
        if (blockIdx.x == 0 && t == NDST / 1024 - 1) off[NDST] = incl;  // grand total
    }
    __syncthreads();
    int p = pfx_s;
    int base = blockIdx.x * 1024 + t * 4;
    int4 v = *(const int4*)(off + base);
    v.x += p; v.y += p; v.z += p; v.w += p;
    *(int4*)(off + base) = v;
    *(int4*)(cur + base) = v;
}

// ---------- CSR fill: both layers, packed int2 {src, weight_bits} records ----------
__global__ void fill_both(const int* __restrict__ src0, const int* __restrict__ dst0,
                          const int* __restrict__ eid0,
                          const int* __restrict__ src1, const int* __restrict__ dst1,
                          const int* __restrict__ eid1,
                          const float* __restrict__ ew,
                          int* __restrict__ cur, int2* __restrict__ recs) {
    int e = blockIdx.x * blockDim.x + threadIdx.x;
    if (e < E0c) {
        int p = atomicAdd(&cur[dst0[e]], 1);
        recs[p] = make_int2(src0[e], __float_as_int(ew[eid0[e]]));
    } else if (e < ETOT) {
        int i = e - E0c;
        int p = atomicAdd(&cur[N1c + dst1[i]], 1);
        recs[p] = make_int2(src1[i], __float_as_int(ew[eid1[i]]));
    }
}

// ---------- fused layer 0: per-block gather (mean+root from f32 x) -> LDS -> MFMA -> bf16 hb ----------
__global__ __launch_bounds__(256) void gemm0_fused(const float* __restrict__ x,
                                                   const int* __restrict__ off,
                                                   const int2* __restrict__ recs,
                                                   const short* __restrict__ Wp,
                                                   const float* __restrict__ bias,
                                                   short* __restrict__ hb) {
    __shared__ short As[32 * 520];   // A-tile: [row][mean 0..255 | root 256..511 | pad 8]
    int t = threadIdx.x, lane = t & 63, w = t >> 6;
    int base = blockIdx.x * 32;

    // gather phase: wave w owns rows w*8 .. w*8+7
    for (int r = 0; r < 8; r++) {
        int rl = w * 8 + r;
        int row = base + rl;
        int s = off[row], e = off[row + 1];
        float4 acc = make_float4(0.f, 0.f, 0.f, 0.f);
        int i = s;
        for (; i + 3 < e; i += 4) {
            int2 r0 = recs[i], r1 = recs[i + 1], r2 = recs[i + 2], r3 = recs[i + 3];
            float w0 = __int_as_float(r0.y), w1 = __int_as_float(r1.y);
            float w2 = __int_as_float(r2.y), w3 = __int_as_float(r3.y);
            float4 v0 = ((const float4*)(x + (size_t)r0.x * Cc))[lane];
            float4 v1 = ((const float4*)(x + (size_t)r1.x * Cc))[lane];
            float4 v2 = ((const float4*)(x + (size_t)r2.x * Cc))[lane];
            float4 v3 = ((const float4*)(x + (size_t)r3.x * Cc))[lane];
            acc.x += w0 * v0.x + w1 * v1.x + w2 * v2.x + w3 * v3.x;
            acc.y += w0 * v0.y + w1 * v1.y + w2 * v2.y + w3 * v3.y;
            acc.z += w0 * v0.z + w1 * v1.z + w2 * v2.z + w3 * v3.z;
            acc.w += w0 * v0.w + w1 * v1.w + w2 * v2.w + w3 * v3.w;
        }
        for (; i < e; i++) {
            int2 rc = recs[i];
            float ww = __int_as_float(rc.y);
            float4 v = ((const float4*)(x + (size_t)rc.x * Cc))[lane];
            acc.x += ww * v.x; acc.y += ww * v.y; acc.z += ww * v.z; acc.w += ww * v.w;
        }
        float inv = 1.0f / fmaxf((float)(e - s), 1.0f);
        ushort4 m;
        m.x = f2bf(acc.x * inv); m.y = f2bf(acc.y * inv);
        m.z = f2bf(acc.z * inv); m.w = f2bf(acc.w * inv);
        *(ushort4*)(&As[rl * 520 + lane * 4]) = m;
        float4 rv = ((const float4*)(x + (size_t)row * Cc))[lane];
        ushort4 ro;
        ro.x = f2bf(rv.x); ro.y = f2bf(rv.y); ro.z = f2bf(rv.z); ro.w = f2bf(rv.w);
        *(ushort4*)(&As[rl * 520 + 256 + lane * 4]) = ro;
    }
    __syncthreads();

    // MFMA phase
    int l15 = lane & 15, lq = lane >> 4;
    floatx4 acc[2][4];
#pragma unroll
    for (int rt = 0; rt < 2; rt++)
#pragma unroll
        for (int ct = 0; ct < 4; ct++) acc[rt][ct] = (floatx4){0.f, 0.f, 0.f, 0.f};
    for (int kt = 0; kt < 16; kt++) {
        short8 a0 = *(const short8*)(&As[l15 * 520 + kt * 32 + lq * 8]);
        short8 a1 = *(const short8*)(&As[(16 + l15) * 520 + kt * 32 + lq * 8]);
#pragma unroll
        for (int ct = 0; ct < 4; ct++) {
            int nt = w * 4 + ct;
            short8 b = *(const short8*)(Wp + (((size_t)nt * 16 + kt) * 64 + lane) * 8);
            acc[0][ct] = __builtin_amdgcn_mfma_f32_16x16x32_bf16(a0, b, acc[0][ct], 0, 0, 0);
            acc[1][ct] = __builtin_amdgcn_mfma_f32_16x16x32_bf16(a1, b, acc[1][ct], 0, 0, 0);
        }
    }
    __syncthreads();   // all As reads done before epilogue overwrite

    // epilogue: bias + relu -> bf16 via LDS (coalesced hb stores)
    short* Os = As;    // 32 x 260 shorts
#pragma unroll
    for (int rt = 0; rt < 2; rt++)
#pragma unroll
        for (int ct = 0; ct < 4; ct++) {
            int col = (w * 4 + ct) * 16 + l15;
            float bv = bias[col];
#pragma unroll
            for (int r = 0; r < 4; r++) {
                int rl = rt * 16 + lq * 4 + r;
                float val = fmaxf(acc[rt][ct][r] + bv, 0.f);
                Os[rl * 260 + col] = (short)f2bf(val);
            }
        }
    __syncthreads();
#pragma unroll
    for (int it = 0; it < 8; it++) {
        int idx = it * 256 + t;
        int row = idx >> 6, c = idx & 63;
        ushort4 v = *(const ushort4*)(&Os[row * 260 + c * 4]);
        *(ushort4*)(hb + (size_t)(base + row) * Cc + c * 4) = v;
    }
}

// ---------- fused layer 1: gather from bf16 hb -> MFMA -> bias -> logits + log_softmax ----------
__global__ __launch_bounds__(256) void gemm1_fused(const short* __restrict__ hb,
                                                   const int* __restrict__ off,
                                                   const int2* __restrict__ recs,
                                                   const short* __restrict__ Wp,
                                                   const float* __restrict__ bias,
                                                   float* __restrict__ out0,
                                                   float* __restrict__ out1) {
    __shared__ short As[32 * 520];
    int t = threadIdx.x, lane = t & 63, w = t >> 6;
    int base = blockIdx.x * 32;

    for (int r = 0; r < 8; r++) {
        int rl = w * 8 + r;
        int row = base + rl;
        int crow = N1c + row;
        int s = off[crow], e = off[crow + 1];
        float4 acc = make_float4(0.f, 0.f, 0.f, 0.f);
        int i = s;
        for (; i + 3 < e; i += 4) {
            int2 r0 = recs[i], r1 = recs[i + 1], r2 = recs[i + 2], r3 = recs[i + 3];
            float w0 = __int_as_float(r0.y), w1 = __int_as_float(r1.y);
            float w2 = __int_as_float(r2.y), w3 = __int_as_float(r3.y);
            ushort4 h0 = ((const ushort4*)(hb + (size_t)r0.x * Cc))[lane];
            ushort4 h1 = ((const ushort4*)(hb + (size_t)r1.x * Cc))[lane];
            ushort4 h2 = ((const ushort4*)(hb + (size_t)r2.x * Cc))[lane];
            ushort4 h3 = ((const ushort4*)(hb + (size_t)r3.x * Cc))[lane];
            acc.x += w0 * bf2f(h0.x) + w1 * bf2f(h1.x) + w2 * bf2f(h2.x) + w3 * bf2f(h3.x);
            acc.y += w0 * bf2f(h0.y) + w1 * bf2f(h1.y) + w2 * bf2f(h2.y) + w3 * bf2f(h3.y);
            acc.z += w0 * bf2f(h0.z) + w1 * bf2f(h1.z) + w2 * bf2f(h2.z) + w3 * bf2f(h3.z);
            acc.w += w0 * bf2f(h0.w) + w1 * bf2f(h1.w) + w2 * bf2f(h2.w) + w3 * bf2f(h3.w);
        }
        for (; i < e; i++) {
            int2 rc = recs[i];
            float ww = __int_as_float(rc.y);
            ushort4 hv = ((const ushort4*)(hb + (size_t)rc.x * Cc))[lane];
            acc.x += ww * bf2f(hv.x); acc.y += ww * bf2f(hv.y);
            acc.z += ww * bf2f(hv.z); acc.w += ww * bf2f(hv.w);
        }
        float inv = 1.0f / fmaxf((float)(e - s), 1.0f);
        ushort4 m;
        m.x = f2bf(acc.x * inv); m.y = f2bf(acc.y * inv);
        m.z = f2bf(acc.z * inv); m.w = f2bf(acc.w * inv);
        *(ushort4*)(&As[rl * 520 + lane * 4]) = m;
        ushort4 ro = ((const ushort4*)(hb + (size_t)row * Cc))[lane];  // root: already bf16
        *(ushort4*)(&As[rl * 520 + 256 + lane * 4]) = ro;
    }
    __syncthreads();

    int l15 = lane & 15, lq = lane >> 4;
    floatx4 acc[2][4];
#pragma unroll
    for (int rt = 0; rt < 2; rt++)
#pragma unroll
        for (int ct = 0; ct < 4; ct++) acc[rt][ct] = (floatx4){0.f, 0.f, 0.f, 0.f};
    for (int kt = 0; kt < 16; kt++) {
        short8 a0 = *(const short8*)(&As[l15 * 520 + kt * 32 + lq * 8]);
        short8 a1 = *(const short8*)(&As[(16 + l15) * 520 + kt * 32 + lq * 8]);
#pragma unroll
        for (int ct = 0; ct < 4; ct++) {
            int nt = w * 4 + ct;
            short8 b = *(const short8*)(Wp + (((size_t)nt * 16 + kt) * 64 + lane) * 8);
            acc[0][ct] = __builtin_amdgcn_mfma_f32_16x16x32_bf16(a0, b, acc[0][ct], 0, 0, 0);
            acc[1][ct] = __builtin_amdgcn_mfma_f32_16x16x32_bf16(a1, b, acc[1][ct], 0, 0, 0);
        }
    }
    __syncthreads();

    float* Ls = (float*)As;          // 32 x 260 f32 logits buffer
#pragma unroll
    for (int rt = 0; rt < 2; rt++)
#pragma unroll
        for (int ct = 0; ct < 4; ct++) {
            int col = (w * 4 + ct) * 16 + l15;
            float bv = bias[col];
#pragma unroll
            for (int r = 0; r < 4; r++) {
                int rl = rt * 16 + lq * 4 + r;
                Ls[rl * 260 + col] = acc[rt][ct][r] + bv;
            }
        }
    __syncthreads();
    for (int rr = 0; rr < 8; rr++) {
        int rl = w * 8 + rr;
        float4 v = *(const float4*)(Ls + rl * 260 + lane * 4);
        *(float4*)(out0 + (size_t)(base + rl) * Cc + lane * 4) = v;   // logits
        float m = fmaxf(fmaxf(v.x, v.y), fmaxf(v.z, v.w));
#pragma unroll
        for (int o = 32; o; o >>= 1) m = fmaxf(m, __shfl_xor(m, o));
        float s = expf(v.x - m) + expf(v.y - m) + expf(v.z - m) + expf(v.w - m);
#pragma unroll
        for (int o = 32; o; o >>= 1) s += __shfl_xor(s, o);
        float lse = m + logf(s);
        float4 o4;
        o4.x = v.x - lse; o4.y = v.y - lse; o4.z = v.z - lse; o4.w = v.w - lse;
        *(float4*)(out1 + (size_t)(base + rl) * Cc + lane * 4) = o4;
    }
}

extern "C" void kernel_launch(void* const* d_in, const int* in_sizes, int n_in,
                              void* d_out, int out_size, void* d_ws, size_t ws_size,
                              hipStream_t stream) {
    const float* x     = (const float*)d_in[0];
    const int*   src0  = (const int*)d_in[1];
    const int*   dst0  = (const int*)d_in[2];
    const int*   eid0  = (const int*)d_in[3];
    const int*   src1  = (const int*)d_in[4];
    const int*   dst1  = (const int*)d_in[5];
    const int*   eid1  = (const int*)d_in[6];
    const float* ew    = (const float*)d_in[7];
    const float* Wrel0 = (const float*)d_in[8];
    const float* b0    = (const float*)d_in[9];
    const float* Wroot0= (const float*)d_in[10];
    const float* Wrel1 = (const float*)d_in[11];
    const float* b1    = (const float*)d_in[12];
    const float* Wroot1= (const float*)d_in[13];

    char* wsb = (char*)d_ws;
    size_t o = 0;
    auto alloc = [&](size_t bytes) { void* p = wsb + o; o += (bytes + 15) & ~(size_t)15; return p; };
    int*   off   = (int*)  alloc((NDST + 1) * 4);
    int*   cnt   = (int*)  alloc(NDST * 4);          // degree, then "cur"
    int2*  recs  = (int2*) alloc(ETOT * 8);
    int*   parts = (int*)  alloc(64 * 4);
    short* Wp0   = (short*)alloc(16 * 16 * 64 * 8 * 2);
    short* Wp1   = (short*)alloc(16 * 16 * 64 * 8 * 2);
    short* hb    = (short*)alloc((size_t)N1c * Cc * 2);

    // ---- CSR build + W pack ----
    hipMemsetAsync(cnt, 0, NDST * sizeof(int), stream);
    prep_kernel<<<ETOT / 256 + 128, 256, 0, stream>>>(dst0, dst1, cnt,
                                                      Wrel0, Wroot0, Wrel1, Wroot1, Wp0, Wp1);
    scan_part<<<NDST / 1024, 256, 0, stream>>>(cnt, off, parts);
    scan_add<<<NDST / 1024, 256, 0, stream>>>(off, cnt, parts);   // cnt becomes cur
    fill_both<<<ETOT / 256, 256, 0, stream>>>(src0, dst0, eid0, src1, dst1, eid1,
                                              ew, cnt, recs);

    // ---- fused layers ----
    gemm0_fused<<<N1c / 32, 256, 0, stream>>>(x, off, recs, Wp0, b0, hb);
    float* out2 = (float*)d_out;
    gemm1_fused<<<NBc / 32, 256, 0, stream>>>(hb, off, recs, Wp1, b1,
                                              out2, out2 + (size_t)NBc * Cc);
}

// Round 7
// 442.845 us; speedup vs baseline: 1.0049x; 1.0049x over previous
//
#include <hip/hip_runtime.h>
#include <cstdint>
#include <cmath>

#define N0c 247808
#define N1c 22528
#define NBc 2048
#define E0c 225280
#define E1c 20480
#define Cc  256
#define NDST (N1c + NBc)          // 24576 = 24*1024 concatenated CSR rows
#define ETOT (E0c + E1c)          // 245760

typedef __attribute__((ext_vector_type(8))) short short8;   // 8 bf16 in 4 VGPRs
typedef __attribute__((ext_vector_type(4))) float floatx4;  // MFMA C/D frag

__device__ inline unsigned short f2bf(float f) {            // f32 -> bf16 RNE
    union { float f; unsigned u; } cv; cv.f = f;
    unsigned u = cv.u;
    u += 0x7fffu + ((u >> 16) & 1u);
    return (unsigned short)(u >> 16);
}
__device__ inline float bf2f(unsigned short u) {            // bf16 -> f32
    union { unsigned u; float f; } cv; cv.u = ((unsigned)u) << 16;
    return cv.f;
}

// ---------- fused prep: degree count (blocks 0..959) + W pack (960..1087) ----------
// pack layout: [nt(16)][kt(16)][lane(64)][8 bf16]; lane holds
// B[k=kt*32+(lane>>4)*8+j][n=nt*16+(lane&15)], W = [Wrel;Wroot] (K=512)
__global__ __launch_bounds__(256) void prep_kernel(
    const int* __restrict__ dst0, const int* __restrict__ dst1, int* __restrict__ cnt,
    const float* __restrict__ Wrel0, const float* __restrict__ Wroot0,
    const float* __restrict__ Wrel1, const float* __restrict__ Wroot1,
    short* __restrict__ Wp0, short* __restrict__ Wp1) {
    int b = blockIdx.x;
    if (b < ETOT / 256) {
        int e = b * 256 + threadIdx.x;
        if (e < E0c) atomicAdd(&cnt[dst0[e]], 1);
        else         atomicAdd(&cnt[N1c + dst1[e - E0c]], 1);
    } else {
        int gid = (b - ETOT / 256) * 256 + threadIdx.x;   // 0..32767
        int lane = gid & 63;
        int kt = (gid >> 6) & 15;
        int nt = (gid >> 10) & 15;
        int layer = gid >> 14;
        const float* Wrel  = layer ? Wrel1  : Wrel0;
        const float* Wroot = layer ? Wroot1 : Wroot0;
        short* Wp = layer ? Wp1 : Wp0;
        int nn = nt * 16 + (lane & 15);
        int kb = kt * 32 + (lane >> 4) * 8;
        short8 v;
#pragma unroll
        for (int j = 0; j < 8; j++) {
            int k = kb + j;
            float f = (k < 256) ? Wrel[k * 256 + nn] : Wroot[(k - 256) * 256 + nn];
            v[j] = (short)f2bf(f);
        }
        *(short8*)(Wp + (((size_t)nt * 16 + kt) * 64 + lane) * 8) = v;
    }
}

// ---------- scan stage 1: per-1024-chunk exclusive scan + chunk totals ----------
__global__ __launch_bounds__(256) void scan_part(const int* __restrict__ in,
                                                 int* __restrict__ out,
                                                 int* __restrict__ partials) {
    __shared__ int wsum[4];
    int t = threadIdx.x, lane = t & 63, w = t >> 6;
    int base = blockIdx.x * 1024 + t * 4;
    int4 v = *(const int4*)(in + base);
    int s = v.x + v.y + v.z + v.w;
    int incl = s;
#pragma unroll
    for (int o = 1; o < 64; o <<= 1) {
        int u = __shfl_up(incl, o);
        if (lane >= o) incl += u;
    }
    if (lane == 63) wsum[w] = incl;
    __syncthreads();
    int woff = 0;
    for (int j = 0; j < w; j++) woff += wsum[j];
    int excl = woff + incl - s;
    int4 o4;
    o4.x = excl; excl += v.x;
    o4.y = excl; excl += v.y;
    o4.z = excl; excl += v.z;
    o4.w = excl; excl += v.w;
    *(int4*)(out + base) = o4;
    if (t == 255) partials[blockIdx.x] = woff + incl;
}

// ---------- scan stage 2: re-scan 24 partials in-wave, add, emit cur & total ----------
__global__ __launch_bounds__(256) void scan_add(int* __restrict__ off, int* __restrict__ cur,
                                                const int* __restrict__ partials) {
    __shared__ int pfx_s;
    int t = threadIdx.x;
    if (t < 32) {
        int v = (t < NDST / 1024) ? partials[t] : 0;
        int incl = v;
#pragma unroll
        for (int o = 1; o < 32; o <<= 1) {
            int u = __shfl_up(incl, o);
            if (t >= o) incl += u;
        }
        if (t == (int)blockIdx.x) pfx_s = incl - v;       // exclusive prefix for this block
        if (blockIdx.x == 0 && t == NDST / 1024 - 1) off[NDST] = incl;  // grand total
    }
    __syncthreads();
    int p = pfx_s;
    int base = blockIdx.x * 1024 + t * 4;
    int4 v = *(const int4*)(off + base);
    v.x += p; v.y += p; v.z += p; v.w += p;
    *(int4*)(off + base) = v;
    *(int4*)(cur + base) = v;
}

// ---------- CSR fill: both layers, packed int2 {src, weight_bits} records ----------
__global__ void fill_both(const int* __restrict__ src0, const int* __restrict__ dst0,
                          const int* __restrict__ eid0,
                          const int* __restrict__ src1, const int* __restrict__ dst1,
                          const int* __restrict__ eid1,
                          const float* __restrict__ ew,
                          int* __restrict__ cur, int2* __restrict__ recs) {
    int e = blockIdx.x * blockDim.x + threadIdx.x;
    if (e < E0c) {
        int p = atomicAdd(&cur[dst0[e]], 1);
        recs[p] = make_int2(src0[e], __float_as_int(ew[eid0[e]]));
    } else if (e < ETOT) {
        int i = e - E0c;
        int p = atomicAdd(&cur[N1c + dst1[i]], 1);
        recs[p] = make_int2(src1[i], __float_as_int(ew[eid1[i]]));
    }
}

// ---------- fused layer 0: per-block gather (mean+root from f32 x) -> LDS -> MFMA -> bf16 hb ----------
__global__ __launch_bounds__(256) void gemm0_fused(const float* __restrict__ x,
                                                   const int* __restrict__ off,
                                                   const int2* __restrict__ recs,
                                                   const short* __restrict__ Wp,
                                                   const float* __restrict__ bias,
                                                   short* __restrict__ hb) {
    __shared__ short As[32 * 520];   // A-tile: [row][mean 0..255 | root 256..511 | pad 8]
    int t = threadIdx.x, lane = t & 63, w = t >> 6;
    int base = blockIdx.x * 32;

    // gather phase: wave w owns rows w*8 .. w*8+7
    for (int r = 0; r < 8; r++) {
        int rl = w * 8 + r;
        int row = base + rl;
        int s = off[row], e = off[row + 1];
        float4 acc = make_float4(0.f, 0.f, 0.f, 0.f);
        int i = s;
        for (; i + 3 < e; i += 4) {
            int2 r0 = recs[i], r1 = recs[i + 1], r2 = recs[i + 2], r3 = recs[i + 3];
            float w0 = __int_as_float(r0.y), w1 = __int_as_float(r1.y);
            float w2 = __int_as_float(r2.y), w3 = __int_as_float(r3.y);
            float4 v0 = ((const float4*)(x + (size_t)r0.x * Cc))[lane];
            float4 v1 = ((const float4*)(x + (size_t)r1.x * Cc))[lane];
            float4 v2 = ((const float4*)(x + (size_t)r2.x * Cc))[lane];
            float4 v3 = ((const float4*)(x + (size_t)r3.x * Cc))[lane];
            acc.x += w0 * v0.x + w1 * v1.x + w2 * v2.x + w3 * v3.x;
            acc.y += w0 * v0.y + w1 * v1.y + w2 * v2.y + w3 * v3.y;
            acc.z += w0 * v0.z + w1 * v1.z + w2 * v2.z + w3 * v3.z;
            acc.w += w0 * v0.w + w1 * v1.w + w2 * v2.w + w3 * v3.w;
        }
        for (; i < e; i++) {
            int2 rc = recs[i];
            float ww = __int_as_float(rc.y);
            float4 v = ((const float4*)(x + (size_t)rc.x * Cc))[lane];
            acc.x += ww * v.x; acc.y += ww * v.y; acc.z += ww * v.z; acc.w += ww * v.w;
        }
        float inv = 1.0f / fmaxf((float)(e - s), 1.0f);
        ushort4 m;
        m.x = f2bf(acc.x * inv); m.y = f2bf(acc.y * inv);
        m.z = f2bf(acc.z * inv); m.w = f2bf(acc.w * inv);
        *(ushort4*)(&As[rl * 520 + lane * 4]) = m;
        float4 rv = ((const float4*)(x + (size_t)row * Cc))[lane];
        ushort4 ro;
        ro.x = f2bf(rv.x); ro.y = f2bf(rv.y); ro.z = f2bf(rv.z); ro.w = f2bf(rv.w);
        *(ushort4*)(&As[rl * 520 + 256 + lane * 4]) = ro;
    }
    __syncthreads();

    // MFMA phase
    int l15 = lane & 15, lq = lane >> 4;
    floatx4 acc[2][4];
#pragma unroll
    for (int rt = 0; rt < 2; rt++)
#pragma unroll
        for (int ct = 0; ct < 4; ct++) acc[rt][ct] = (floatx4){0.f, 0.f, 0.f, 0.f};
    for (int kt = 0; kt < 16; kt++) {
        short8 a0 = *(const short8*)(&As[l15 * 520 + kt * 32 + lq * 8]);
        short8 a1 = *(const short8*)(&As[(16 + l15) * 520 + kt * 32 + lq * 8]);
#pragma unroll
        for (int ct = 0; ct < 4; ct++) {
            int nt = w * 4 + ct;
            short8 b = *(const short8*)(Wp + (((size_t)nt * 16 + kt) * 64 + lane) * 8);
            acc[0][ct] = __builtin_amdgcn_mfma_f32_16x16x32_bf16(a0, b, acc[0][ct], 0, 0, 0);
            acc[1][ct] = __builtin_amdgcn_mfma_f32_16x16x32_bf16(a1, b, acc[1][ct], 0, 0, 0);
        }
    }
    __syncthreads();   // all As reads done before epilogue overwrite

    // epilogue: bias + relu -> bf16 via LDS (coalesced hb stores)
    short* Os = As;    // 32 x 260 shorts
#pragma unroll
    for (int rt = 0; rt < 2; rt++)
#pragma unroll
        for (int ct = 0; ct < 4; ct++) {
            int col = (w * 4 + ct) * 16 + l15;
            float bv = bias[col];
#pragma unroll
            for (int r = 0; r < 4; r++) {
                int rl = rt * 16 + lq * 4 + r;
                float val = fmaxf(acc[rt][ct][r] + bv, 0.f);
                Os[rl * 260 + col] = (short)f2bf(val);
            }
        }
    __syncthreads();
#pragma unroll
    for (int it = 0; it < 8; it++) {
        int idx = it * 256 + t;
        int row = idx >> 6, c = idx & 63;
        ushort4 v = *(const ushort4*)(&Os[row * 260 + c * 4]);
        *(ushort4*)(hb + (size_t)(base + row) * Cc + c * 4) = v;
    }
}

// ---------- fused layer 1: gather from bf16 hb -> MFMA -> bias -> logits + log_softmax ----------
__global__ __launch_bounds__(256) void gemm1_fused(const short* __restrict__ hb,
                                                   const int* __restrict__ off,
                                                   const int2* __restrict__ recs,
                                                   const short* __restrict__ Wp,
                                                   const float* __restrict__ bias,
                                                   float* __restrict__ out0,
                                                   float* __restrict__ out1) {
    __shared__ short As[32 * 520];
    int t = threadIdx.x, lane = t & 63, w = t >> 6;
    int base = blockIdx.x * 32;

    for (int r = 0; r < 8; r++) {
        int rl = w * 8 + r;
        int row = base + rl;
        int crow = N1c + row;
        int s = off[crow], e = off[crow + 1];
        float4 acc = make_float4(0.f, 0.f, 0.f, 0.f);
        int i = s;
        for (; i + 3 < e; i += 4) {
            int2 r0 = recs[i], r1 = recs[i + 1], r2 = recs[i + 2], r3 = recs[i + 3];
            float w0 = __int_as_float(r0.y), w1 = __int_as_float(r1.y);
            float w2 = __int_as_float(r2.y), w3 = __int_as_float(r3.y);
            ushort4 h0 = ((const ushort4*)(hb + (size_t)r0.x * Cc))[lane];
            ushort4 h1 = ((const ushort4*)(hb + (size_t)r1.x * Cc))[lane];
            ushort4 h2 = ((const ushort4*)(hb + (size_t)r2.x * Cc))[lane];
            ushort4 h3 = ((const ushort4*)(hb + (size_t)r3.x * Cc))[lane];
            acc.x += w0 * bf2f(h0.x) + w1 * bf2f(h1.x) + w2 * bf2f(h2.x) + w3 * bf2f(h3.x);
            acc.y += w0 * bf2f(h0.y) + w1 * bf2f(h1.y) + w2 * bf2f(h2.y) + w3 * bf2f(h3.y);
            acc.z += w0 * bf2f(h0.z) + w1 * bf2f(h1.z) + w2 * bf2f(h2.z) + w3 * bf2f(h3.z);
            acc.w += w0 * bf2f(h0.w) + w1 * bf2f(h1.w) + w2 * bf2f(h2.w) + w3 * bf2f(h3.w);
        }
        for (; i < e; i++) {
            int2 rc = recs[i];
            float ww = __int_as_float(rc.y);
            ushort4 hv = ((const ushort4*)(hb + (size_t)rc.x * Cc))[lane];
            acc.x += ww * bf2f(hv.x); acc.y += ww * bf2f(hv.y);
            acc.z += ww * bf2f(hv.z); acc.w += ww * bf2f(hv.w);
        }
        float inv = 1.0f / fmaxf((float)(e - s), 1.0f);
        ushort4 m;
        m.x = f2bf(acc.x * inv); m.y = f2bf(acc.y * inv);
        m.z = f2bf(acc.z * inv); m.w = f2bf(acc.w * inv);
        *(ushort4*)(&As[rl * 520 + lane * 4]) = m;
        ushort4 ro = ((const ushort4*)(hb + (size_t)row * Cc))[lane];  // root: already bf16
        *(ushort4*)(&As[rl * 520 + 256 + lane * 4]) = ro;
    }
    __syncthreads();

    int l15 = lane & 15, lq = lane >> 4;
    floatx4 acc[2][4];
#pragma unroll
    for (int rt = 0; rt < 2; rt++)
#pragma unroll
        for (int ct = 0; ct < 4; ct++) acc[rt][ct] = (floatx4){0.f, 0.f, 0.f, 0.f};
    for (int kt = 0; kt < 16; kt++) {
        short8 a0 = *(const short8*)(&As[l15 * 520 + kt * 32 + lq * 8]);
        short8 a1 = *(const short8*)(&As[(16 + l15) * 520 + kt * 32 + lq * 8]);
#pragma unroll
        for (int ct = 0; ct < 4; ct++) {
            int nt = w * 4 + ct;
            short8 b = *(const short8*)(Wp + (((size_t)nt * 16 + kt) * 64 + lane) * 8);
            acc[0][ct] = __builtin_amdgcn_mfma_f32_16x16x32_bf16(a0, b, acc[0][ct], 0, 0, 0);
            acc[1][ct] = __builtin_amdgcn_mfma_f32_16x16x32_bf16(a1, b, acc[1][ct], 0, 0, 0);
        }
    }
    __syncthreads();

    float* Ls = (float*)As;          // 32 x 260 f32 logits buffer
#pragma unroll
    for (int rt = 0; rt < 2; rt++)
#pragma unroll
        for (int ct = 0; ct < 4; ct++) {
            int col = (w * 4 + ct) * 16 + l15;
            float bv = bias[col];
#pragma unroll
            for (int r = 0; r < 4; r++) {
                int rl = rt * 16 + lq * 4 + r;
                Ls[rl * 260 + col] = acc[rt][ct][r] + bv;
            }
        }
    __syncthreads();
    for (int rr = 0; rr < 8; rr++) {
        int rl = w * 8 + rr;
        float4 v = *(const float4*)(Ls + rl * 260 + lane * 4);
        *(float4*)(out0 + (size_t)(base + rl) * Cc + lane * 4) = v;   // logits
        float m = fmaxf(fmaxf(v.x, v.y), fmaxf(v.z, v.w));
#pragma unroll
        for (int o = 32; o; o >>= 1) m = fmaxf(m, __shfl_xor(m, o));
        float s = expf(v.x - m) + expf(v.y - m) + expf(v.z - m) + expf(v.w - m);
#pragma unroll
        for (int o = 32; o; o >>= 1) s += __shfl_xor(s, o);
        float lse = m + logf(s);
        float4 o4;
        o4.x = v.x - lse; o4.y = v.y - lse; o4.z = v.z - lse; o4.w = v.w - lse;
        *(float4*)(out1 + (size_t)(base + rl) * Cc + lane * 4) = o4;
    }
}

extern "C" void kernel_launch(void* const* d_in, const int* in_sizes, int n_in,
                              void* d_out, int out_size, void* d_ws, size_t ws_size,
                              hipStream_t stream) {
    const float* x     = (const float*)d_in[0];
    const int*   src0  = (const int*)d_in[1];
    const int*   dst0  = (const int*)d_in[2];
    const int*   eid0  = (const int*)d_in[3];
    const int*   src1  = (const int*)d_in[4];
    const int*   dst1  = (const int*)d_in[5];
    const int*   eid1  = (const int*)d_in[6];
    const float* ew    = (const float*)d_in[7];
    const float* Wrel0 = (const float*)d_in[8];
    const float* b0    = (const float*)d_in[9];
    const float* Wroot0= (const float*)d_in[10];
    const float* Wrel1 = (const float*)d_in[11];
    const float* b1    = (const float*)d_in[12];
    const float* Wroot1= (const float*)d_in[13];

    char* wsb = (char*)d_ws;
    size_t o = 0;
    auto alloc = [&](size_t bytes) { void* p = wsb + o; o += (bytes + 15) & ~(size_t)15; return p; };
    int*   off   = (int*)  alloc((NDST + 1) * 4);
    int*   cnt   = (int*)  alloc(NDST * 4);          // degree, then "cur"
    int2*  recs  = (int2*) alloc(ETOT * 8);
    int*   parts = (int*)  alloc(64 * 4);
    short* Wp0   = (short*)alloc(16 * 16 * 64 * 8 * 2);
    short* Wp1   = (short*)alloc(16 * 16 * 64 * 8 * 2);
    short* hb    = (short*)alloc((size_t)N1c * Cc * 2);

    // ---- CSR build + W pack ----
    hipMemsetAsync(cnt, 0, NDST * sizeof(int), stream);
    prep_kernel<<<ETOT / 256 + 128, 256, 0, stream>>>(dst0, dst1, cnt,
                                                      Wrel0, Wroot0, Wrel1, Wroot1, Wp0, Wp1);
    scan_part<<<NDST / 1024, 256, 0, stream>>>(cnt, off, parts);
    scan_add<<<NDST / 1024, 256, 0, stream>>>(off, cnt, parts);   // cnt becomes cur
    fill_both<<<ETOT / 256, 256, 0, stream>>>(src0, dst0, eid0, src1, dst1, eid1,
                                              ew, cnt, recs);

    // ---- fused layers ----
    gemm0_fused<<<N1c / 32, 256, 0, stream>>>(x, off, recs, Wp0, b0, hb);
    float* out2 = (float*)d_out;
    gemm1_fused<<<NBc / 32, 256, 0, stream>>>(hb, off, recs, Wp1, b1,
                                              out2, out2 + (size_t)NBc * Cc);
}